// Round 11
// baseline (193.634 us; speedup 1.0000x reference)
//
#include <hip/hip_runtime.h>

#define BN_EPS 1e-5f

using f32x4 = __attribute__((ext_vector_type(4))) float;
using s16x8 = __attribute__((ext_vector_type(8))) short;
using u32x4 = __attribute__((ext_vector_type(4))) unsigned int;

__device__ __forceinline__ unsigned short f2bf(float f) {
    unsigned u = __float_as_uint(f);
    u += 0x7fffu + ((u >> 16) & 1u);   // round-to-nearest-even
    return (unsigned short)(u >> 16);
}
__device__ __forceinline__ float bflo(unsigned u) { return __uint_as_float(u << 16); }
__device__ __forceinline__ float bfhi(unsigned u) { return __uint_as_float(u & 0xffff0000u); }

// ---------------- CSR build ----------------
__global__ void hist_kernel(const int* __restrict__ dst, int* __restrict__ deg, int e) {
    int i = blockIdx.x * blockDim.x + threadIdx.x;
    if (i < e) atomicAdd(&deg[dst[i]], 1);
}

__global__ void scan_excl(const int* __restrict__ deg, int* __restrict__ rowstart, int n) {
    __shared__ int wsum[16];
    int tid = threadIdx.x;
    int per = (n + 1023) >> 10;
    int b0 = tid * per;
    int s = 0;
    for (int j = 0; j < per; ++j) {
        int i = b0 + j;
        if (i < n) s += deg[i];
    }
    int lane = tid & 63, w = tid >> 6;
    int v = s;
    #pragma unroll
    for (int off = 1; off < 64; off <<= 1) {
        int t = __shfl_up(v, off, 64);
        if (lane >= off) v += t;
    }
    if (lane == 63) wsum[w] = v;
    __syncthreads();
    if (w == 0) {
        int t = (lane < 16) ? wsum[lane] : 0;
        #pragma unroll
        for (int off = 1; off < 16; off <<= 1) {
            int u = __shfl_up(t, off, 64);
            if (lane >= off) t += u;
        }
        if (lane < 16) wsum[lane] = t;
    }
    __syncthreads();
    int base = (w > 0 ? wsum[w - 1] : 0) + v - s;
    for (int j = 0; j < per; ++j) {
        int i = b0 + j;
        if (i < n) { rowstart[i] = base; base += deg[i]; }
    }
    if (tid == 0) rowstart[n] = wsum[15];
}

__global__ void scatter_kernel(const int* __restrict__ src, const int* __restrict__ dst,
                               const float* __restrict__ ea,
                               const int* __restrict__ rowstart, int* __restrict__ cursor,
                               int2* __restrict__ sae, int e) {
    int i = blockIdx.x * blockDim.x + threadIdx.x;
    if (i < e) {
        int d = dst[i];
        int pos = atomicAdd(&cursor[d], 1);
        sae[rowstart[d] + pos] = make_int2(src[i], __float_as_int(ea[i]));
    }
}

// ---------------- prep: weight transposes + x->bf16 + bias concat + zero-init ----------------
__global__ __launch_bounds__(256) void prep_kernel(
    const float* __restrict__ x,
    const float* __restrict__ Wq1, const float* __restrict__ Wk1,
    const float* __restrict__ Wv1, const float* __restrict__ Ws1,
    const float* __restrict__ bq1, const float* __restrict__ bk1,
    const float* __restrict__ bv1, const float* __restrict__ bs1,
    const float* __restrict__ Wq2, const float* __restrict__ Wk2,
    const float* __restrict__ Wv2, const float* __restrict__ Ws2,
    const float* __restrict__ bq2, const float* __restrict__ bk2,
    const float* __restrict__ bv2, const float* __restrict__ bs2,
    unsigned short* __restrict__ xb, unsigned short* __restrict__ Wt1,
    unsigned short* __restrict__ Wt2, float* __restrict__ bcat1, float* __restrict__ bcat2,
    int* __restrict__ deg, int* __restrict__ cursor,
    float* __restrict__ bns1P, float* __restrict__ bns2P, int N, int n4) {
    __shared__ unsigned short t[64][65];
    int bid = blockIdx.x;
    if (bid < 96) {
        int K, b;
        const float *Wq, *Wk, *Wv, *Ws;
        unsigned short* Wt;
        if (bid < 32) { K = 128; b = bid; Wq = Wq1; Wk = Wk1; Wv = Wv1; Ws = Ws1; Wt = Wt1; }
        else          { K = 256; b = bid - 32; Wq = Wq2; Wk = Wk2; Wv = Wv2; Ws = Ws2; Wt = Wt2; }
        int k0 = (b >> 4) * 64, c0 = (b & 15) * 64;
        const float* W = (c0 < 256) ? Wq : (c0 < 512) ? Wk : (c0 < 768) ? Wv : Ws;
        int cc = c0 & 255;
        int tr = threadIdx.x >> 6;
        int tc = threadIdx.x & 63;
        #pragma unroll
        for (int r = tr; r < 64; r += 4)
            t[r][tc] = f2bf(W[(size_t)(k0 + r) * 256 + cc + tc]);
        __syncthreads();
        #pragma unroll
        for (int r = tr; r < 64; r += 4)
            Wt[(size_t)(c0 + r) * K + k0 + tc] = t[tc][r];
    } else {
        int idx = (bid - 96) * 256 + threadIdx.x;
        if (idx < n4) {
            float4 v = ((const float4*)x)[idx];
            ushort4 o;
            o.x = f2bf(v.x); o.y = f2bf(v.y); o.z = f2bf(v.z); o.w = f2bf(v.w);
            ((ushort4*)xb)[idx] = o;
        }
        if (idx < N) { deg[idx] = 0; cursor[idx] = 0; }
        if (idx < 4096) { bns1P[idx] = 0.f; bns2P[idx] = 0.f; }   // 8 x 512 partials each
        if (idx < 1024) {
            const float* b1 = (idx < 256) ? bq1 : (idx < 512) ? bk1 : (idx < 768) ? bv1 : bs1;
            const float* b2 = (idx < 256) ? bq2 : (idx < 512) ? bk2 : (idx < 768) ? bv2 : bs2;
            bcat1[idx] = b1[idx & 255];
            bcat2[idx] = b2[idx & 255];
        }
    }
}

// ---------------- bf16 MFMA GEMM: [Q|K|V|S] = A[M][K] x Bt[1024][K]^T + bias ----------------
// FUSED: A is fp32 [M][256] pre-BN; BN stats arrive as 8 replicated partials (bns[8][512]).
// XCD swizzle: all 8 col-panels of a row-strip share blockIdx%8 -> same XCD L2.
__global__ __launch_bounds__(256) void gemm_core(const unsigned short* __restrict__ Ab,
                                                 const float* __restrict__ Af,
                                                 const unsigned short* __restrict__ Bt,
                                                 const float* __restrict__ bias,
                                                 const float* __restrict__ bns,
                                                 const float* __restrict__ bng,
                                                 const float* __restrict__ bnb,
                                                 float invn, int FUSED_BN,
                                                 float* __restrict__ Qf,
                                                 unsigned short* __restrict__ KVb,
                                                 float* __restrict__ Sf,
                                                 int M, int K, int gx) {
    __shared__ unsigned short As[128][72];
    __shared__ unsigned short Bs[128][72];
    __shared__ float bnsc[256], bnsh[256];
    const int b = blockIdx.x;
    const int bx = (b >> 6) * 8 + (b & 7);   // row-strip
    const int by = (b >> 3) & 7;             // col-panel
    if (bx >= gx) return;
    const int tid = threadIdx.x;
    const int lane = tid & 63;
    const int wave = tid >> 6;
    const int wr = (wave >> 1) * 64;
    const int wc = (wave & 1) * 64;
    const int g = lane >> 4;
    const int r16 = lane & 15;
    const int rowBase = bx * 128;
    const int colBase = by * 128;
    const int srow = tid >> 1;
    const int skh = (tid & 1) * 32;

    if (FUSED_BN) {
        int c = tid;
        float s = 0.f, s2 = 0.f;
        #pragma unroll
        for (int k = 0; k < 8; ++k) {
            s  += bns[k * 512 + c];
            s2 += bns[k * 512 + 256 + c];
        }
        float mu = s * invn;
        float var = s2 * invn - mu * mu;
        float sc = rsqrtf(var + BN_EPS) * bng[c];
        bnsc[c] = sc;
        bnsh[c] = bnb[c] - mu * sc;
        __syncthreads();
    }

    f32x4 acc[4][4];
    #pragma unroll
    for (int i = 0; i < 4; ++i)
        #pragma unroll
        for (int j = 0; j < 4; ++j)
            acc[i][j] = (f32x4){0.f, 0.f, 0.f, 0.f};

    for (int k0 = 0; k0 < K; k0 += 64) {
        {
            int grow = rowBase + srow;
            bool ok = grow < M;
            if (FUSED_BN) {
                if (ok) {
                    const float* pa = &Af[(size_t)grow * K + k0 + skh];
                    #pragma unroll
                    for (int i = 0; i < 4; ++i) {
                        int kk = k0 + skh + i * 8;
                        f32x4 lo = *(const f32x4*)(pa + i * 8);
                        f32x4 hi = *(const f32x4*)(pa + i * 8 + 4);
                        u32x4 wrd;
                        #pragma unroll
                        for (int e = 0; e < 2; ++e) {
                            unsigned a0 = f2bf(fmaxf(lo[2*e]   * bnsc[kk+2*e]   + bnsh[kk+2*e],   0.f));
                            unsigned a1 = f2bf(fmaxf(lo[2*e+1] * bnsc[kk+2*e+1] + bnsh[kk+2*e+1], 0.f));
                            unsigned a2 = f2bf(fmaxf(hi[2*e]   * bnsc[kk+4+2*e]   + bnsh[kk+4+2*e],   0.f));
                            unsigned a3 = f2bf(fmaxf(hi[2*e+1] * bnsc[kk+4+2*e+1] + bnsh[kk+4+2*e+1], 0.f));
                            wrd[e] = a0 | (a1 << 16);
                            wrd[2 + e] = a2 | (a3 << 16);
                        }
                        *(u32x4*)&As[srow][skh + i * 8] = wrd;
                    }
                } else {
                    #pragma unroll
                    for (int i = 0; i < 4; ++i)
                        *(u32x4*)&As[srow][skh + i * 8] = (u32x4){0u, 0u, 0u, 0u};
                }
            } else {
                const unsigned short* pa = &Ab[(size_t)(ok ? grow : 0) * K + k0 + skh];
                #pragma unroll
                for (int i = 0; i < 4; ++i) {
                    u32x4 v = ok ? *(const u32x4*)(pa + i * 8) : (u32x4){0u, 0u, 0u, 0u};
                    *(u32x4*)&As[srow][skh + i * 8] = v;
                }
            }
            const unsigned short* pb = &Bt[(size_t)(colBase + srow) * K + k0 + skh];
            #pragma unroll
            for (int i = 0; i < 4; ++i)
                *(u32x4*)&Bs[srow][skh + i * 8] = *(const u32x4*)(pb + i * 8);
        }
        __syncthreads();
        #pragma unroll
        for (int kk = 0; kk < 64; kk += 32) {
            s16x8 af[4], bf[4];
            #pragma unroll
            for (int i = 0; i < 4; ++i) af[i] = *(const s16x8*)&As[wr + i * 16 + r16][kk + g * 8];
            #pragma unroll
            for (int j = 0; j < 4; ++j) bf[j] = *(const s16x8*)&Bs[wc + j * 16 + r16][kk + g * 8];
            #pragma unroll
            for (int i = 0; i < 4; ++i)
                #pragma unroll
                for (int j = 0; j < 4; ++j)
                    acc[i][j] = __builtin_amdgcn_mfma_f32_16x16x32_bf16(af[i], bf[j], acc[i][j], 0, 0, 0);
        }
        __syncthreads();
    }

    #pragma unroll
    for (int j = 0; j < 4; ++j) {
        int gcol = colBase + wc + j * 16 + r16;
        int panel = gcol >> 8;
        int pc = gcol & 255;
        float bb = bias[gcol];
        #pragma unroll
        for (int i = 0; i < 4; ++i) {
            #pragma unroll
            for (int r = 0; r < 4; ++r) {
                int grow = rowBase + wr + i * 16 + g * 4 + r;
                if (grow < M) {
                    float val = acc[i][j][r] + bb;
                    if (panel == 0)      Qf[(size_t)grow * 256 + pc] = val;
                    else if (panel == 1) KVb[(size_t)grow * 512 + pc] = f2bf(val);
                    else if (panel == 2) KVb[(size_t)grow * 512 + 256 + pc] = f2bf(val);
                    else                 Sf[(size_t)grow * 256 + pc] = val;
                }
            }
        }
    }
}

// ---------------- attention: one wave per dst node, NO-MAX softmax, fused BN partial stats ----------------
// Epilogue accumulates {sum, sumsq} per channel in LDS across the block's 4 nodes, then one
// atomicAdd per channel into an 8-way replicated partial buffer (contention /8).
__global__ __launch_bounds__(256) void attn_kernel(const float* __restrict__ Qf,
                                                   const unsigned short* __restrict__ KVb,
                                                   const float* __restrict__ Sf,
                                                   const int2* __restrict__ sae,
                                                   const float* __restrict__ We,
                                                   const int* __restrict__ rowstart,
                                                   float* __restrict__ out,
                                                   float* __restrict__ bnsP, int n) {
    __shared__ float sm[512];
    int tid = threadIdx.x;
    sm[tid] = 0.f;
    sm[tid + 256] = 0.f;
    __syncthreads();

    int wave = tid >> 6, lane = tid & 63;
    int node = blockIdx.x * 4 + wave;
    bool active = node < n;
    int epar = lane >> 5;
    int hc = ((lane >> 4) & 1) * 128 + (lane & 15) * 8;

    if (active) {
        float4 qa = *(const float4*)&Qf[(size_t)node * 256 + hc];
        float4 qb = *(const float4*)&Qf[(size_t)node * 256 + hc + 4];
        float4 wea = *(const float4*)&We[hc];
        float4 web = *(const float4*)&We[hc + 4];
        float q[8]  = {qa.x, qa.y, qa.z, qa.w, qb.x, qb.y, qb.z, qb.w};
        float wv[8] = {wea.x, wea.y, wea.z, wea.w, web.x, web.y, web.z, web.w};

        const float scale = 0.08838834764831845f;   // 1/sqrt(128)
        float qwe = 0.f;
        #pragma unroll
        for (int t = 0; t < 8; ++t) qwe += q[t] * wv[t];
        qwe += __shfl_xor(qwe, 1, 64);
        qwe += __shfl_xor(qwe, 2, 64);
        qwe += __shfl_xor(qwe, 4, 64);
        qwe += __shfl_xor(qwe, 8, 64);
        float qwes = qwe * scale;

        int beg = rowstart[node], end = rowstart[node + 1];
        const unsigned short* KV = KVb + hc;

        float ssum = 0.f, wa = 0.f;
        float acc[8] = {0.f, 0.f, 0.f, 0.f, 0.f, 0.f, 0.f, 0.f};

        auto process = [&](const u32x4& kk, const u32x4& vv, float a, bool valid) {
            float s = 0.f;
            #pragma unroll
            for (int t = 0; t < 4; ++t)
                s += q[2 * t] * bflo(kk[t]) + q[2 * t + 1] * bfhi(kk[t]);
            s += __shfl_xor(s, 1, 64);
            s += __shfl_xor(s, 2, 64);
            s += __shfl_xor(s, 4, 64);
            s += __shfl_xor(s, 8, 64);
            float w = valid ? __expf(s * scale + a * qwes) : 0.f;
            ssum += w;
            wa += w * a;
            #pragma unroll
            for (int t = 0; t < 4; ++t) {
                acc[2 * t]     += w * bflo(vv[t]);
                acc[2 * t + 1] += w * bfhi(vv[t]);
            }
        };

        for (int i0 = beg; i0 < end; i0 += 8) {
            bool val[4];
            float aval[4];
            u32x4 kw[4], vw[4];
            #pragma unroll
            for (int j = 0; j < 4; ++j) {
                int i = i0 + 2 * j + epar;
                val[j] = i < end;
                int2 se = sae[val[j] ? i : beg];
                aval[j] = __int_as_float(se.y);
                const unsigned short* kp = KV + (size_t)se.x * 512;
                kw[j] = *(const u32x4*)kp;
                vw[j] = *(const u32x4*)(kp + 256);
            }
            #pragma unroll
            for (int j = 0; j < 4; ++j)
                process(kw[j], vw[j], aval[j], val[j]);
        }

        // merge the two edge-slot partials (lane ^ 32)
        float sw = ssum + __shfl_xor(ssum, 32, 64);
        float waw = wa + __shfl_xor(wa, 32, 64);
        float o[8];
        #pragma unroll
        for (int t = 0; t < 8; ++t)
            o[t] = acc[t] + __shfl_xor(acc[t], 32, 64);

        if (epar == 0) {
            float inv = 1.0f / (sw + 1e-16f);
            float4 sk0 = *(const float4*)&Sf[(size_t)node * 256 + hc];
            float4 sk1 = *(const float4*)&Sf[(size_t)node * 256 + hc + 4];
            float r[8];
            r[0] = (o[0] + waw * wv[0]) * inv + sk0.x;
            r[1] = (o[1] + waw * wv[1]) * inv + sk0.y;
            r[2] = (o[2] + waw * wv[2]) * inv + sk0.z;
            r[3] = (o[3] + waw * wv[3]) * inv + sk0.w;
            r[4] = (o[4] + waw * wv[4]) * inv + sk1.x;
            r[5] = (o[5] + waw * wv[5]) * inv + sk1.y;
            r[6] = (o[6] + waw * wv[6]) * inv + sk1.z;
            r[7] = (o[7] + waw * wv[7]) * inv + sk1.w;
            *(float4*)&out[(size_t)node * 256 + hc] = make_float4(r[0], r[1], r[2], r[3]);
            *(float4*)&out[(size_t)node * 256 + hc + 4] = make_float4(r[4], r[5], r[6], r[7]);
            // BN partial stats: channels hc..hc+7 distinct per lane within the wave
            #pragma unroll
            for (int t = 0; t < 8; ++t) {
                atomicAdd(&sm[hc + t], r[t]);
                atomicAdd(&sm[256 + hc + t], r[t] * r[t]);
            }
        }
    }

    __syncthreads();
    float* dstp = bnsP + (blockIdx.x & 7) * 512;
    atomicAdd(&dstp[tid], sm[tid]);
    atomicAdd(&dstp[tid + 256], sm[tid + 256]);
}

// ---------------- BatchNorm apply (stats from 8 replicated partials) ----------------
__global__ __launch_bounds__(256) void bn_apply(const float* __restrict__ x,
                                                const float* __restrict__ bnsP,
                                                const float* __restrict__ g,
                                                const float* __restrict__ b,
                                                float* __restrict__ y, int n, float invn) {
    __shared__ float sc_s[256], sh_s[256];
    int tid = threadIdx.x;
    {
        float s = 0.f, s2 = 0.f;
        #pragma unroll
        for (int k = 0; k < 8; ++k) {
            s  += bnsP[k * 512 + tid];
            s2 += bnsP[k * 512 + 256 + tid];
        }
        float mu = s * invn;
        float var = s2 * invn - mu * mu;
        float sc = rsqrtf(var + BN_EPS) * g[tid];
        sc_s[tid] = sc;
        sh_s[tid] = b[tid] - mu * sc;
    }
    __syncthreads();
    for (int r = blockIdx.x; r < n; r += gridDim.x) {
        float v = x[(size_t)r * 256 + tid] * sc_s[tid] + sh_s[tid];
        y[(size_t)r * 256 + tid] = fmaxf(v, 0.f);
    }
}

extern "C" void kernel_launch(void* const* d_in, const int* in_sizes, int n_in,
                              void* d_out, int out_size, void* d_ws, size_t ws_size,
                              hipStream_t stream) {
    const float* x         = (const float*)d_in[0];
    const int*   edge_idx  = (const int*)d_in[1];
    const float* edge_attr = (const float*)d_in[2];
    const float* Wq1 = (const float*)d_in[3];  const float* bq1 = (const float*)d_in[4];
    const float* Wk1 = (const float*)d_in[5];  const float* bk1 = (const float*)d_in[6];
    const float* Wv1 = (const float*)d_in[7];  const float* bv1 = (const float*)d_in[8];
    const float* We1 = (const float*)d_in[9];
    const float* Ws1 = (const float*)d_in[10]; const float* bs1 = (const float*)d_in[11];
    const float* g1  = (const float*)d_in[12]; const float* b1  = (const float*)d_in[13];
    const float* Wq2 = (const float*)d_in[14]; const float* bq2 = (const float*)d_in[15];
    const float* Wk2 = (const float*)d_in[16]; const float* bk2 = (const float*)d_in[17];
    const float* Wv2 = (const float*)d_in[18]; const float* bv2 = (const float*)d_in[19];
    const float* We2 = (const float*)d_in[20];
    const float* Ws2 = (const float*)d_in[21]; const float* bs2 = (const float*)d_in[22];
    const float* g2  = (const float*)d_in[23]; const float* b2  = (const float*)d_in[24];

    const int N = in_sizes[0] / 128;   // 10000
    const int E = in_sizes[1] / 2;     // 160000
    const int* src = edge_idx;
    const int* dst = edge_idx + E;

    char* ws = (char*)d_ws;
    size_t off = 0;
    auto alloc = [&](size_t bytes) -> void* {
        void* p = ws + off;
        off += (bytes + 255) & ~(size_t)255;
        return p;
    };
    float*          Qf       = (float*)alloc((size_t)N * 256 * 4);
    unsigned short* KVb      = (unsigned short*)alloc((size_t)N * 512 * 2);
    float*          Sf       = (float*)alloc((size_t)N * 256 * 4);
    float*          attn_out = (float*)alloc((size_t)N * 256 * 4);
    unsigned short* xb       = (unsigned short*)alloc((size_t)N * 128 * 2);
    unsigned short* Wt1      = (unsigned short*)alloc((size_t)1024 * 128 * 2);
    unsigned short* Wt2      = (unsigned short*)alloc((size_t)1024 * 256 * 2);
    float*          bcat1    = (float*)alloc(1024 * 4);
    float*          bcat2    = (float*)alloc(1024 * 4);
    int*            deg      = (int*)alloc((size_t)N * 4);
    int*            rowstart = (int*)alloc((size_t)(N + 1) * 4);
    int*            cursor   = (int*)alloc((size_t)N * 4);
    int2*           sae      = (int2*)alloc((size_t)E * 8);
    float*          bns1P    = (float*)alloc(8 * 512 * 4);
    float*          bns2P    = (float*)alloc(8 * 512 * 4);

    const int n4 = N * 128 / 4;
    const float invn = 1.0f / (float)N;

    prep_kernel<<<96 + (n4 + 255) / 256, 256, 0, stream>>>(
        x, Wq1, Wk1, Wv1, Ws1, bq1, bk1, bv1, bs1,
        Wq2, Wk2, Wv2, Ws2, bq2, bk2, bv2, bs2,
        xb, Wt1, Wt2, bcat1, bcat2, deg, cursor, bns1P, bns2P, N, n4);
    hist_kernel<<<(E + 255) / 256, 256, 0, stream>>>(dst, deg, E);
    scan_excl<<<1, 1024, 0, stream>>>(deg, rowstart, N);
    scatter_kernel<<<(E + 255) / 256, 256, 0, stream>>>(src, dst, edge_attr, rowstart, cursor,
                                                        sae, E);

    const int gx = (N + 127) / 128;                 // 79 row-strips
    const int gemm_blocks = ((gx + 7) / 8) * 64;    // swizzled 1D grid (some blocks idle)
    int attn_blocks = (N + 3) / 4;

    // ---- layer 1 (K = 128) ----
    gemm_core<<<gemm_blocks, 256, 0, stream>>>(xb, nullptr, Wt1, bcat1,
                                               nullptr, nullptr, nullptr, 0.f, 0,
                                               Qf, KVb, Sf, N, 128, gx);
    attn_kernel<<<attn_blocks, 256, 0, stream>>>(Qf, KVb, Sf, sae, We1, rowstart,
                                                 attn_out, bns1P, N);

    // ---- layer 2 (K = 256), BN1+ReLU+bf16 fused into A-staging ----
    gemm_core<<<gemm_blocks, 256, 0, stream>>>(nullptr, attn_out, Wt2, bcat2,
                                               bns1P, g1, b1, invn, 1,
                                               Qf, KVb, Sf, N, 256, gx);
    attn_kernel<<<attn_blocks, 256, 0, stream>>>(Qf, KVb, Sf, sae, We2, rowstart,
                                                 attn_out, bns2P, N);
    bn_apply<<<1024, 256, 0, stream>>>(attn_out, bns2P, g2, b2, (float*)d_out, N, invn);
}

// Round 12
// 177.144 us; speedup vs baseline: 1.0931x; 1.0931x over previous
//
#include <hip/hip_runtime.h>

#define BN_EPS 1e-5f

using f32x4 = __attribute__((ext_vector_type(4))) float;
using s16x8 = __attribute__((ext_vector_type(8))) short;
using u32x4 = __attribute__((ext_vector_type(4))) unsigned int;

__device__ __forceinline__ unsigned short f2bf(float f) {
    unsigned u = __float_as_uint(f);
    u += 0x7fffu + ((u >> 16) & 1u);   // round-to-nearest-even
    return (unsigned short)(u >> 16);
}
__device__ __forceinline__ float bflo(unsigned u) { return __uint_as_float(u << 16); }
__device__ __forceinline__ float bfhi(unsigned u) { return __uint_as_float(u & 0xffff0000u); }

// ---------------- CSR build ----------------
__global__ void hist_kernel(const int* __restrict__ dst, int* __restrict__ deg, int e) {
    int i = blockIdx.x * blockDim.x + threadIdx.x;
    if (i < e) atomicAdd(&deg[dst[i]], 1);
}

__global__ void scan_excl(const int* __restrict__ deg, int* __restrict__ rowstart, int n) {
    __shared__ int wsum[16];
    int tid = threadIdx.x;
    int per = (n + 1023) >> 10;
    int b0 = tid * per;
    int s = 0;
    for (int j = 0; j < per; ++j) {
        int i = b0 + j;
        if (i < n) s += deg[i];
    }
    int lane = tid & 63, w = tid >> 6;
    int v = s;
    #pragma unroll
    for (int off = 1; off < 64; off <<= 1) {
        int t = __shfl_up(v, off, 64);
        if (lane >= off) v += t;
    }
    if (lane == 63) wsum[w] = v;
    __syncthreads();
    if (w == 0) {
        int t = (lane < 16) ? wsum[lane] : 0;
        #pragma unroll
        for (int off = 1; off < 16; off <<= 1) {
            int u = __shfl_up(t, off, 64);
            if (lane >= off) t += u;
        }
        if (lane < 16) wsum[lane] = t;
    }
    __syncthreads();
    int base = (w > 0 ? wsum[w - 1] : 0) + v - s;
    for (int j = 0; j < per; ++j) {
        int i = b0 + j;
        if (i < n) { rowstart[i] = base; base += deg[i]; }
    }
    if (tid == 0) rowstart[n] = wsum[15];
}

__global__ void scatter_kernel(const int* __restrict__ src, const int* __restrict__ dst,
                               const float* __restrict__ ea,
                               const int* __restrict__ rowstart, int* __restrict__ cursor,
                               int2* __restrict__ sae, int e) {
    int i = blockIdx.x * blockDim.x + threadIdx.x;
    if (i < e) {
        int d = dst[i];
        int pos = atomicAdd(&cursor[d], 1);
        sae[rowstart[d] + pos] = make_int2(src[i], __float_as_int(ea[i]));
    }
}

// ---------------- prep: weight transposes + x->bf16 + bias concat + zero-init ----------------
__global__ __launch_bounds__(256) void prep_kernel(
    const float* __restrict__ x,
    const float* __restrict__ Wq1, const float* __restrict__ Wk1,
    const float* __restrict__ Wv1, const float* __restrict__ Ws1,
    const float* __restrict__ bq1, const float* __restrict__ bk1,
    const float* __restrict__ bv1, const float* __restrict__ bs1,
    const float* __restrict__ Wq2, const float* __restrict__ Wk2,
    const float* __restrict__ Wv2, const float* __restrict__ Ws2,
    const float* __restrict__ bq2, const float* __restrict__ bk2,
    const float* __restrict__ bv2, const float* __restrict__ bs2,
    unsigned short* __restrict__ xb, unsigned short* __restrict__ Wt1,
    unsigned short* __restrict__ Wt2, float* __restrict__ bcat1, float* __restrict__ bcat2,
    int* __restrict__ deg, int* __restrict__ cursor,
    float* __restrict__ bns1, float* __restrict__ bns2, int N, int n4) {
    __shared__ unsigned short t[64][65];
    int bid = blockIdx.x;
    if (bid < 96) {
        int K, b;
        const float *Wq, *Wk, *Wv, *Ws;
        unsigned short* Wt;
        if (bid < 32) { K = 128; b = bid; Wq = Wq1; Wk = Wk1; Wv = Wv1; Ws = Ws1; Wt = Wt1; }
        else          { K = 256; b = bid - 32; Wq = Wq2; Wk = Wk2; Wv = Wv2; Ws = Ws2; Wt = Wt2; }
        int k0 = (b >> 4) * 64, c0 = (b & 15) * 64;
        const float* W = (c0 < 256) ? Wq : (c0 < 512) ? Wk : (c0 < 768) ? Wv : Ws;
        int cc = c0 & 255;
        int tr = threadIdx.x >> 6;
        int tc = threadIdx.x & 63;
        #pragma unroll
        for (int r = tr; r < 64; r += 4)
            t[r][tc] = f2bf(W[(size_t)(k0 + r) * 256 + cc + tc]);
        __syncthreads();
        #pragma unroll
        for (int r = tr; r < 64; r += 4)
            Wt[(size_t)(c0 + r) * K + k0 + tc] = t[tc][r];
    } else {
        int idx = (bid - 96) * 256 + threadIdx.x;
        if (idx < n4) {
            float4 v = ((const float4*)x)[idx];
            ushort4 o;
            o.x = f2bf(v.x); o.y = f2bf(v.y); o.z = f2bf(v.z); o.w = f2bf(v.w);
            ((ushort4*)xb)[idx] = o;
        }
        if (idx < N) { deg[idx] = 0; cursor[idx] = 0; }
        if (idx < 512) { bns1[idx] = 0.f; bns2[idx] = 0.f; }
        if (idx < 1024) {
            const float* b1 = (idx < 256) ? bq1 : (idx < 512) ? bk1 : (idx < 768) ? bv1 : bs1;
            const float* b2 = (idx < 256) ? bq2 : (idx < 512) ? bk2 : (idx < 768) ? bv2 : bs2;
            bcat1[idx] = b1[idx & 255];
            bcat2[idx] = b2[idx & 255];
        }
    }
}

// ---------------- bf16 MFMA GEMM: [Q|K|V|S] = A[M][K] x Bt[1024][K]^T + bias ----------------
// A is always bf16. FUSED: apply BN (x*scale+shift), relu, re-round in A-staging.
// XCD swizzle: all 8 col-panels of a row-strip share blockIdx%8 -> same XCD L2.
template <int FUSED>
__global__ __launch_bounds__(256) void gemm_core(const unsigned short* __restrict__ Ab,
                                                 const unsigned short* __restrict__ Bt,
                                                 const float* __restrict__ bias,
                                                 const float* __restrict__ bns,
                                                 const float* __restrict__ bng,
                                                 const float* __restrict__ bnb,
                                                 float invn,
                                                 float* __restrict__ Qf,
                                                 unsigned short* __restrict__ KVb,
                                                 float* __restrict__ Sf,
                                                 int M, int K, int gx) {
    __shared__ unsigned short As[128][72];
    __shared__ unsigned short Bs[128][72];
    __shared__ float bnsc[256], bnsh[256];
    const int b = blockIdx.x;
    const int bx = (b >> 6) * 8 + (b & 7);   // row-strip
    const int by = (b >> 3) & 7;             // col-panel
    if (bx >= gx) return;
    const int tid = threadIdx.x;
    const int lane = tid & 63;
    const int wave = tid >> 6;
    const int wr = (wave >> 1) * 64;
    const int wc = (wave & 1) * 64;
    const int g = lane >> 4;
    const int r16 = lane & 15;
    const int rowBase = bx * 128;
    const int colBase = by * 128;
    const int srow = tid >> 1;
    const int skh = (tid & 1) * 32;

    if (FUSED) {
        int c = tid;
        float s = bns[c], s2 = bns[256 + c];
        float mu = s * invn;
        float var = s2 * invn - mu * mu;
        float sc = rsqrtf(var + BN_EPS) * bng[c];
        bnsc[c] = sc;
        bnsh[c] = bnb[c] - mu * sc;
        __syncthreads();
    }

    f32x4 acc[4][4];
    #pragma unroll
    for (int i = 0; i < 4; ++i)
        #pragma unroll
        for (int j = 0; j < 4; ++j)
            acc[i][j] = (f32x4){0.f, 0.f, 0.f, 0.f};

    for (int k0 = 0; k0 < K; k0 += 64) {
        {
            int grow = rowBase + srow;
            bool ok = grow < M;
            const unsigned short* pa = &Ab[(size_t)(ok ? grow : 0) * K + k0 + skh];
            #pragma unroll
            for (int i = 0; i < 4; ++i) {
                u32x4 v = ok ? *(const u32x4*)(pa + i * 8) : (u32x4){0u, 0u, 0u, 0u};
                if (FUSED) {
                    if (ok) {
                        int kk = k0 + skh + i * 8;
                        u32x4 o;
                        #pragma unroll
                        for (int e = 0; e < 4; ++e) {
                            float f0 = bflo(v[e]) * bnsc[kk + 2 * e]     + bnsh[kk + 2 * e];
                            float f1 = bfhi(v[e]) * bnsc[kk + 2 * e + 1] + bnsh[kk + 2 * e + 1];
                            o[e] = (unsigned)f2bf(fmaxf(f0, 0.f)) |
                                   ((unsigned)f2bf(fmaxf(f1, 0.f)) << 16);
                        }
                        v = o;
                    }
                }
                *(u32x4*)&As[srow][skh + i * 8] = v;
            }
            const unsigned short* pb = &Bt[(size_t)(colBase + srow) * K + k0 + skh];
            #pragma unroll
            for (int i = 0; i < 4; ++i)
                *(u32x4*)&Bs[srow][skh + i * 8] = *(const u32x4*)(pb + i * 8);
        }
        __syncthreads();
        #pragma unroll
        for (int kk = 0; kk < 64; kk += 32) {
            s16x8 af[4], bf[4];
            #pragma unroll
            for (int i = 0; i < 4; ++i) af[i] = *(const s16x8*)&As[wr + i * 16 + r16][kk + g * 8];
            #pragma unroll
            for (int j = 0; j < 4; ++j) bf[j] = *(const s16x8*)&Bs[wc + j * 16 + r16][kk + g * 8];
            #pragma unroll
            for (int i = 0; i < 4; ++i)
                #pragma unroll
                for (int j = 0; j < 4; ++j)
                    acc[i][j] = __builtin_amdgcn_mfma_f32_16x16x32_bf16(af[i], bf[j], acc[i][j], 0, 0, 0);
        }
        __syncthreads();
    }

    #pragma unroll
    for (int j = 0; j < 4; ++j) {
        int gcol = colBase + wc + j * 16 + r16;
        int panel = gcol >> 8;
        int pc = gcol & 255;
        float bb = bias[gcol];
        #pragma unroll
        for (int i = 0; i < 4; ++i) {
            #pragma unroll
            for (int r = 0; r < 4; ++r) {
                int grow = rowBase + wr + i * 16 + g * 4 + r;
                if (grow < M) {
                    float val = acc[i][j][r] + bb;
                    if (panel == 0)      Qf[(size_t)grow * 256 + pc] = val;
                    else if (panel == 1) KVb[(size_t)grow * 512 + pc] = f2bf(val);
                    else if (panel == 2) KVb[(size_t)grow * 512 + 256 + pc] = f2bf(val);
                    else                 Sf[(size_t)grow * 256 + pc] = val;
                }
            }
        }
    }
}

// ---------------- attention: one wave per dst node, NO-MAX softmax, 8 edges in flight ----------------
template <int OUTBF>
__global__ __launch_bounds__(256) void attn_kernel(const float* __restrict__ Qf,
                                                   const unsigned short* __restrict__ KVb,
                                                   const float* __restrict__ Sf,
                                                   const int2* __restrict__ sae,
                                                   const float* __restrict__ We,
                                                   const int* __restrict__ rowstart,
                                                   float* __restrict__ outf,
                                                   unsigned short* __restrict__ outb, int n) {
    int wave = threadIdx.x >> 6, lane = threadIdx.x & 63;
    int node = blockIdx.x * 4 + wave;
    if (node >= n) return;
    int epar = lane >> 5;
    int hc = ((lane >> 4) & 1) * 128 + (lane & 15) * 8;

    float4 qa = *(const float4*)&Qf[(size_t)node * 256 + hc];
    float4 qb = *(const float4*)&Qf[(size_t)node * 256 + hc + 4];
    float4 wea = *(const float4*)&We[hc];
    float4 web = *(const float4*)&We[hc + 4];
    float q[8]  = {qa.x, qa.y, qa.z, qa.w, qb.x, qb.y, qb.z, qb.w};
    float wv[8] = {wea.x, wea.y, wea.z, wea.w, web.x, web.y, web.z, web.w};

    const float scale = 0.08838834764831845f;   // 1/sqrt(128)
    float qwe = 0.f;
    #pragma unroll
    for (int t = 0; t < 8; ++t) qwe += q[t] * wv[t];
    qwe += __shfl_xor(qwe, 1, 64);
    qwe += __shfl_xor(qwe, 2, 64);
    qwe += __shfl_xor(qwe, 4, 64);
    qwe += __shfl_xor(qwe, 8, 64);
    float qwes = qwe * scale;

    int beg = rowstart[node], end = rowstart[node + 1];
    const unsigned short* KV = KVb + hc;

    float ssum = 0.f, wa = 0.f;
    float acc[8] = {0.f, 0.f, 0.f, 0.f, 0.f, 0.f, 0.f, 0.f};

    auto process = [&](const u32x4& kk, const u32x4& vv, float a, bool valid) {
        float s = 0.f;
        #pragma unroll
        for (int t = 0; t < 4; ++t)
            s += q[2 * t] * bflo(kk[t]) + q[2 * t + 1] * bfhi(kk[t]);
        s += __shfl_xor(s, 1, 64);
        s += __shfl_xor(s, 2, 64);
        s += __shfl_xor(s, 4, 64);
        s += __shfl_xor(s, 8, 64);
        float w = valid ? __expf(s * scale + a * qwes) : 0.f;
        ssum += w;
        wa += w * a;
        #pragma unroll
        for (int t = 0; t < 4; ++t) {
            acc[2 * t]     += w * bflo(vv[t]);
            acc[2 * t + 1] += w * bfhi(vv[t]);
        }
    };

    for (int i0 = beg; i0 < end; i0 += 8) {
        bool val[4];
        float aval[4];
        u32x4 kw[4], vw[4];
        #pragma unroll
        for (int j = 0; j < 4; ++j) {
            int i = i0 + 2 * j + epar;
            val[j] = i < end;
            int2 se = sae[val[j] ? i : beg];
            aval[j] = __int_as_float(se.y);
            const unsigned short* kp = KV + (size_t)se.x * 512;
            kw[j] = *(const u32x4*)kp;
            vw[j] = *(const u32x4*)(kp + 256);
        }
        #pragma unroll
        for (int j = 0; j < 4; ++j)
            process(kw[j], vw[j], aval[j], val[j]);
    }

    // merge the two edge-slot partials (lane ^ 32)
    float sw = ssum + __shfl_xor(ssum, 32, 64);
    float waw = wa + __shfl_xor(wa, 32, 64);
    float o[8];
    #pragma unroll
    for (int t = 0; t < 8; ++t)
        o[t] = acc[t] + __shfl_xor(acc[t], 32, 64);

    if (epar == 0) {
        float inv = 1.0f / (sw + 1e-16f);
        float4 sk0 = *(const float4*)&Sf[(size_t)node * 256 + hc];
        float4 sk1 = *(const float4*)&Sf[(size_t)node * 256 + hc + 4];
        float r[8];
        r[0] = (o[0] + waw * wv[0]) * inv + sk0.x;
        r[1] = (o[1] + waw * wv[1]) * inv + sk0.y;
        r[2] = (o[2] + waw * wv[2]) * inv + sk0.z;
        r[3] = (o[3] + waw * wv[3]) * inv + sk0.w;
        r[4] = (o[4] + waw * wv[4]) * inv + sk1.x;
        r[5] = (o[5] + waw * wv[5]) * inv + sk1.y;
        r[6] = (o[6] + waw * wv[6]) * inv + sk1.z;
        r[7] = (o[7] + waw * wv[7]) * inv + sk1.w;
        if (OUTBF) {
            u32x4 ob;
            #pragma unroll
            for (int t = 0; t < 4; ++t)
                ob[t] = (unsigned)f2bf(r[2 * t]) | ((unsigned)f2bf(r[2 * t + 1]) << 16);
            *(u32x4*)&outb[(size_t)node * 256 + hc] = ob;
        } else {
            *(float4*)&outf[(size_t)node * 256 + hc] = make_float4(r[0], r[1], r[2], r[3]);
            *(float4*)&outf[(size_t)node * 256 + hc + 4] = make_float4(r[4], r[5], r[6], r[7]);
        }
    }
}

// ---------------- BatchNorm ----------------
template <int BF>
__global__ void bn_stats(const void* __restrict__ xv, float* __restrict__ sums, int n) {
    int c = threadIdx.x;  // 256
    float s = 0.f, s2 = 0.f;
    if (BF) {
        const unsigned short* x = (const unsigned short*)xv;
        for (int r = blockIdx.x; r < n; r += gridDim.x) {
            float v = __uint_as_float((unsigned)x[(size_t)r * 256 + c] << 16);
            s += v; s2 += v * v;
        }
    } else {
        const float* x = (const float*)xv;
        for (int r = blockIdx.x; r < n; r += gridDim.x) {
            float v = x[(size_t)r * 256 + c];
            s += v; s2 += v * v;
        }
    }
    atomicAdd(&sums[c], s);
    atomicAdd(&sums[256 + c], s2);
}

__global__ void bn_apply(const float* __restrict__ x, const float* __restrict__ sums,
                         const float* __restrict__ g, const float* __restrict__ b,
                         float* __restrict__ y, int n) {
    int idx = blockIdx.x * blockDim.x + threadIdx.x;
    if (idx >= n * 256) return;
    int c = idx & 255;
    float invn = 1.0f / (float)n;
    float mu = sums[c] * invn;
    float var = sums[256 + c] * invn - mu * mu;
    float v = (x[idx] - mu) * rsqrtf(var + BN_EPS) * g[c] + b[c];
    y[idx] = fmaxf(v, 0.f);
}

extern "C" void kernel_launch(void* const* d_in, const int* in_sizes, int n_in,
                              void* d_out, int out_size, void* d_ws, size_t ws_size,
                              hipStream_t stream) {
    const float* x         = (const float*)d_in[0];
    const int*   edge_idx  = (const int*)d_in[1];
    const float* edge_attr = (const float*)d_in[2];
    const float* Wq1 = (const float*)d_in[3];  const float* bq1 = (const float*)d_in[4];
    const float* Wk1 = (const float*)d_in[5];  const float* bk1 = (const float*)d_in[6];
    const float* Wv1 = (const float*)d_in[7];  const float* bv1 = (const float*)d_in[8];
    const float* We1 = (const float*)d_in[9];
    const float* Ws1 = (const float*)d_in[10]; const float* bs1 = (const float*)d_in[11];
    const float* g1  = (const float*)d_in[12]; const float* b1  = (const float*)d_in[13];
    const float* Wq2 = (const float*)d_in[14]; const float* bq2 = (const float*)d_in[15];
    const float* Wk2 = (const float*)d_in[16]; const float* bk2 = (const float*)d_in[17];
    const float* Wv2 = (const float*)d_in[18]; const float* bv2 = (const float*)d_in[19];
    const float* We2 = (const float*)d_in[20];
    const float* Ws2 = (const float*)d_in[21]; const float* bs2 = (const float*)d_in[22];
    const float* g2  = (const float*)d_in[23]; const float* b2  = (const float*)d_in[24];

    const int N = in_sizes[0] / 128;   // 10000
    const int E = in_sizes[1] / 2;     // 160000
    const int* src = edge_idx;
    const int* dst = edge_idx + E;

    char* ws = (char*)d_ws;
    size_t off = 0;
    auto alloc = [&](size_t bytes) -> void* {
        void* p = ws + off;
        off += (bytes + 255) & ~(size_t)255;
        return p;
    };
    float*          Qf       = (float*)alloc((size_t)N * 256 * 4);
    unsigned short* KVb      = (unsigned short*)alloc((size_t)N * 512 * 2);
    float*          Sf       = (float*)alloc((size_t)N * 256 * 4);
    float*          attn_out = (float*)alloc((size_t)N * 256 * 4);
    unsigned short* h1b      = (unsigned short*)alloc((size_t)N * 256 * 2);
    unsigned short* xb       = (unsigned short*)alloc((size_t)N * 128 * 2);
    unsigned short* Wt1      = (unsigned short*)alloc((size_t)1024 * 128 * 2);
    unsigned short* Wt2      = (unsigned short*)alloc((size_t)1024 * 256 * 2);
    float*          bcat1    = (float*)alloc(1024 * 4);
    float*          bcat2    = (float*)alloc(1024 * 4);
    int*            deg      = (int*)alloc((size_t)N * 4);
    int*            rowstart = (int*)alloc((size_t)(N + 1) * 4);
    int*            cursor   = (int*)alloc((size_t)N * 4);
    int2*           sae      = (int2*)alloc((size_t)E * 8);
    float*          bns1     = (float*)alloc(512 * 4);
    float*          bns2     = (float*)alloc(512 * 4);

    const int n4 = N * 128 / 4;
    const float invn = 1.0f / (float)N;

    prep_kernel<<<96 + (n4 + 255) / 256, 256, 0, stream>>>(
        x, Wq1, Wk1, Wv1, Ws1, bq1, bk1, bv1, bs1,
        Wq2, Wk2, Wv2, Ws2, bq2, bk2, bv2, bs2,
        xb, Wt1, Wt2, bcat1, bcat2, deg, cursor, bns1, bns2, N, n4);
    hist_kernel<<<(E + 255) / 256, 256, 0, stream>>>(dst, deg, E);
    scan_excl<<<1, 1024, 0, stream>>>(deg, rowstart, N);
    scatter_kernel<<<(E + 255) / 256, 256, 0, stream>>>(src, dst, edge_attr, rowstart, cursor,
                                                        sae, E);

    const int gx = (N + 127) / 128;                 // 79 row-strips
    const int gemm_blocks = ((gx + 7) / 8) * 64;    // swizzled 1D grid (some blocks idle)
    int attn_blocks = (N + 3) / 4;

    // ---- layer 1 (K = 128) ----
    gemm_core<0><<<gemm_blocks, 256, 0, stream>>>(xb, Wt1, bcat1, nullptr, nullptr, nullptr, 0.f,
                                                  Qf, KVb, Sf, N, 128, gx);
    attn_kernel<1><<<attn_blocks, 256, 0, stream>>>(Qf, KVb, Sf, sae, We1, rowstart,
                                                    nullptr, h1b, N);
    bn_stats<1><<<256, 256, 0, stream>>>(h1b, bns1, N);

    // ---- layer 2 (K = 256), BN1+ReLU fused into A-staging (bf16 h1) ----
    gemm_core<1><<<gemm_blocks, 256, 0, stream>>>(h1b, Wt2, bcat2, bns1, g1, b1, invn,
                                                  Qf, KVb, Sf, N, 256, gx);
    attn_kernel<0><<<attn_blocks, 256, 0, stream>>>(Qf, KVb, Sf, sae, We2, rowstart,
                                                    attn_out, nullptr, N);
    bn_stats<0><<<256, 256, 0, stream>>>(attn_out, bns2, N);
    bn_apply<<<(N * 256 + 255) / 256, 256, 0, stream>>>(attn_out, bns2, g2, b2, (float*)d_out, N);
}

// Round 13
// 174.889 us; speedup vs baseline: 1.1072x; 1.0129x over previous
//
#include <hip/hip_runtime.h>

#define BN_EPS 1e-5f

using f32x4 = __attribute__((ext_vector_type(4))) float;
using s16x8 = __attribute__((ext_vector_type(8))) short;
using u32x4 = __attribute__((ext_vector_type(4))) unsigned int;

__device__ __forceinline__ unsigned short f2bf(float f) {
    unsigned u = __float_as_uint(f);
    u += 0x7fffu + ((u >> 16) & 1u);   // round-to-nearest-even
    return (unsigned short)(u >> 16);
}
__device__ __forceinline__ float bflo(unsigned u) { return __uint_as_float(u << 16); }
__device__ __forceinline__ float bfhi(unsigned u) { return __uint_as_float(u & 0xffff0000u); }

// ---------------- CSR build ----------------
__global__ void hist_kernel(const int* __restrict__ dst, int* __restrict__ deg, int e) {
    int i = blockIdx.x * blockDim.x + threadIdx.x;
    if (i < e) atomicAdd(&deg[dst[i]], 1);
}

__global__ void scan_excl(const int* __restrict__ deg, int* __restrict__ rowstart, int n) {
    __shared__ int wsum[16];
    int tid = threadIdx.x;
    int per = (n + 1023) >> 10;
    int b0 = tid * per;
    int s = 0;
    for (int j = 0; j < per; ++j) {
        int i = b0 + j;
        if (i < n) s += deg[i];
    }
    int lane = tid & 63, w = tid >> 6;
    int v = s;
    #pragma unroll
    for (int off = 1; off < 64; off <<= 1) {
        int t = __shfl_up(v, off, 64);
        if (lane >= off) v += t;
    }
    if (lane == 63) wsum[w] = v;
    __syncthreads();
    if (w == 0) {
        int t = (lane < 16) ? wsum[lane] : 0;
        #pragma unroll
        for (int off = 1; off < 16; off <<= 1) {
            int u = __shfl_up(t, off, 64);
            if (lane >= off) t += u;
        }
        if (lane < 16) wsum[lane] = t;
    }
    __syncthreads();
    int base = (w > 0 ? wsum[w - 1] : 0) + v - s;
    for (int j = 0; j < per; ++j) {
        int i = b0 + j;
        if (i < n) { rowstart[i] = base; base += deg[i]; }
    }
    if (tid == 0) rowstart[n] = wsum[15];
}

__global__ void scatter_kernel(const int* __restrict__ src, const int* __restrict__ dst,
                               const float* __restrict__ ea,
                               const int* __restrict__ rowstart, int* __restrict__ cursor,
                               int2* __restrict__ sae, int e) {
    int i = blockIdx.x * blockDim.x + threadIdx.x;
    if (i < e) {
        int d = dst[i];
        int pos = atomicAdd(&cursor[d], 1);
        sae[rowstart[d] + pos] = make_int2(src[i], __float_as_int(ea[i]));
    }
}

// ---------------- prep: weight transposes + x->bf16 + bias concat + zero-init ----------------
__global__ __launch_bounds__(256) void prep_kernel(
    const float* __restrict__ x,
    const float* __restrict__ Wq1, const float* __restrict__ Wk1,
    const float* __restrict__ Wv1, const float* __restrict__ Ws1,
    const float* __restrict__ bq1, const float* __restrict__ bk1,
    const float* __restrict__ bv1, const float* __restrict__ bs1,
    const float* __restrict__ Wq2, const float* __restrict__ Wk2,
    const float* __restrict__ Wv2, const float* __restrict__ Ws2,
    const float* __restrict__ bq2, const float* __restrict__ bk2,
    const float* __restrict__ bv2, const float* __restrict__ bs2,
    unsigned short* __restrict__ xb, unsigned short* __restrict__ Wt1,
    unsigned short* __restrict__ Wt2, float* __restrict__ bcat1, float* __restrict__ bcat2,
    int* __restrict__ deg, int* __restrict__ cursor,
    float* __restrict__ bns1, float* __restrict__ bns2, int N, int n4) {
    __shared__ unsigned short t[64][65];
    int bid = blockIdx.x;
    if (bid < 96) {
        int K, b;
        const float *Wq, *Wk, *Wv, *Ws;
        unsigned short* Wt;
        if (bid < 32) { K = 128; b = bid; Wq = Wq1; Wk = Wk1; Wv = Wv1; Ws = Ws1; Wt = Wt1; }
        else          { K = 256; b = bid - 32; Wq = Wq2; Wk = Wk2; Wv = Wv2; Ws = Ws2; Wt = Wt2; }
        int k0 = (b >> 4) * 64, c0 = (b & 15) * 64;
        const float* W = (c0 < 256) ? Wq : (c0 < 512) ? Wk : (c0 < 768) ? Wv : Ws;
        int cc = c0 & 255;
        int tr = threadIdx.x >> 6;
        int tc = threadIdx.x & 63;
        #pragma unroll
        for (int r = tr; r < 64; r += 4)
            t[r][tc] = f2bf(W[(size_t)(k0 + r) * 256 + cc + tc]);
        __syncthreads();
        #pragma unroll
        for (int r = tr; r < 64; r += 4)
            Wt[(size_t)(c0 + r) * K + k0 + tc] = t[tc][r];
    } else {
        int idx = (bid - 96) * 256 + threadIdx.x;
        if (idx < n4) {
            float4 v = ((const float4*)x)[idx];
            ushort4 o;
            o.x = f2bf(v.x); o.y = f2bf(v.y); o.z = f2bf(v.z); o.w = f2bf(v.w);
            ((ushort4*)xb)[idx] = o;
        }
        if (idx < N) { deg[idx] = 0; cursor[idx] = 0; }
        if (idx < 512) { bns1[idx] = 0.f; bns2[idx] = 0.f; }
        if (idx < 1024) {
            const float* b1 = (idx < 256) ? bq1 : (idx < 512) ? bk1 : (idx < 768) ? bv1 : bs1;
            const float* b2 = (idx < 256) ? bq2 : (idx < 512) ? bk2 : (idx < 768) ? bv2 : bs2;
            bcat1[idx] = b1[idx & 255];
            bcat2[idx] = b2[idx & 255];
        }
    }
}

// ---------------- bf16 MFMA GEMM: [Q|K|V|S] = A[M][K] x Bt[1024][K]^T + bias ----------------
// All four output panels bf16 now: Qb [M][256], KVb [M][512], Sb [M][256].
// FUSED: apply BN (x*scale+shift), relu, re-round in A-staging.
// XCD swizzle: all 8 col-panels of a row-strip share blockIdx%8 -> same XCD L2.
template <int FUSED>
__global__ __launch_bounds__(256) void gemm_core(const unsigned short* __restrict__ Ab,
                                                 const unsigned short* __restrict__ Bt,
                                                 const float* __restrict__ bias,
                                                 const float* __restrict__ bns,
                                                 const float* __restrict__ bng,
                                                 const float* __restrict__ bnb,
                                                 float invn,
                                                 unsigned short* __restrict__ Qb,
                                                 unsigned short* __restrict__ KVb,
                                                 unsigned short* __restrict__ Sb,
                                                 int M, int K, int gx) {
    __shared__ unsigned short As[128][72];
    __shared__ unsigned short Bs[128][72];
    __shared__ float bnsc[256], bnsh[256];
    const int b = blockIdx.x;
    const int bx = (b >> 6) * 8 + (b & 7);   // row-strip
    const int by = (b >> 3) & 7;             // col-panel
    if (bx >= gx) return;
    const int tid = threadIdx.x;
    const int lane = tid & 63;
    const int wave = tid >> 6;
    const int wr = (wave >> 1) * 64;
    const int wc = (wave & 1) * 64;
    const int g = lane >> 4;
    const int r16 = lane & 15;
    const int rowBase = bx * 128;
    const int colBase = by * 128;
    const int srow = tid >> 1;
    const int skh = (tid & 1) * 32;

    if (FUSED) {
        int c = tid;
        float s = bns[c], s2 = bns[256 + c];
        float mu = s * invn;
        float var = s2 * invn - mu * mu;
        float sc = rsqrtf(var + BN_EPS) * bng[c];
        bnsc[c] = sc;
        bnsh[c] = bnb[c] - mu * sc;
        __syncthreads();
    }

    f32x4 acc[4][4];
    #pragma unroll
    for (int i = 0; i < 4; ++i)
        #pragma unroll
        for (int j = 0; j < 4; ++j)
            acc[i][j] = (f32x4){0.f, 0.f, 0.f, 0.f};

    for (int k0 = 0; k0 < K; k0 += 64) {
        {
            int grow = rowBase + srow;
            bool ok = grow < M;
            const unsigned short* pa = &Ab[(size_t)(ok ? grow : 0) * K + k0 + skh];
            #pragma unroll
            for (int i = 0; i < 4; ++i) {
                u32x4 v = ok ? *(const u32x4*)(pa + i * 8) : (u32x4){0u, 0u, 0u, 0u};
                if (FUSED) {
                    if (ok) {
                        int kk = k0 + skh + i * 8;
                        u32x4 o;
                        #pragma unroll
                        for (int e = 0; e < 4; ++e) {
                            float f0 = bflo(v[e]) * bnsc[kk + 2 * e]     + bnsh[kk + 2 * e];
                            float f1 = bfhi(v[e]) * bnsc[kk + 2 * e + 1] + bnsh[kk + 2 * e + 1];
                            o[e] = (unsigned)f2bf(fmaxf(f0, 0.f)) |
                                   ((unsigned)f2bf(fmaxf(f1, 0.f)) << 16);
                        }
                        v = o;
                    }
                }
                *(u32x4*)&As[srow][skh + i * 8] = v;
            }
            const unsigned short* pb = &Bt[(size_t)(colBase + srow) * K + k0 + skh];
            #pragma unroll
            for (int i = 0; i < 4; ++i)
                *(u32x4*)&Bs[srow][skh + i * 8] = *(const u32x4*)(pb + i * 8);
        }
        __syncthreads();
        #pragma unroll
        for (int kk = 0; kk < 64; kk += 32) {
            s16x8 af[4], bf[4];
            #pragma unroll
            for (int i = 0; i < 4; ++i) af[i] = *(const s16x8*)&As[wr + i * 16 + r16][kk + g * 8];
            #pragma unroll
            for (int j = 0; j < 4; ++j) bf[j] = *(const s16x8*)&Bs[wc + j * 16 + r16][kk + g * 8];
            #pragma unroll
            for (int i = 0; i < 4; ++i)
                #pragma unroll
                for (int j = 0; j < 4; ++j)
                    acc[i][j] = __builtin_amdgcn_mfma_f32_16x16x32_bf16(af[i], bf[j], acc[i][j], 0, 0, 0);
        }
        __syncthreads();
    }

    #pragma unroll
    for (int j = 0; j < 4; ++j) {
        int gcol = colBase + wc + j * 16 + r16;
        int panel = gcol >> 8;
        int pc = gcol & 255;
        float bb = bias[gcol];
        #pragma unroll
        for (int i = 0; i < 4; ++i) {
            #pragma unroll
            for (int r = 0; r < 4; ++r) {
                int grow = rowBase + wr + i * 16 + g * 4 + r;
                if (grow < M) {
                    float val = acc[i][j][r] + bb;
                    unsigned short bv = f2bf(val);
                    if (panel == 0)      Qb[(size_t)grow * 256 + pc] = bv;
                    else if (panel == 1) KVb[(size_t)grow * 512 + pc] = bv;
                    else if (panel == 2) KVb[(size_t)grow * 512 + 256 + pc] = bv;
                    else                 Sb[(size_t)grow * 256 + pc] = bv;
                }
            }
        }
    }
}

// ---------------- attention: one wave per dst node, NO-MAX softmax, 8 edges in flight ----------------
template <int OUTBF>
__global__ __launch_bounds__(256) void attn_kernel(const unsigned short* __restrict__ Qb,
                                                   const unsigned short* __restrict__ KVb,
                                                   const unsigned short* __restrict__ Sb,
                                                   const int2* __restrict__ sae,
                                                   const float* __restrict__ We,
                                                   const int* __restrict__ rowstart,
                                                   float* __restrict__ outf,
                                                   unsigned short* __restrict__ outb, int n) {
    int wave = threadIdx.x >> 6, lane = threadIdx.x & 63;
    int node = blockIdx.x * 4 + wave;
    if (node >= n) return;
    int epar = lane >> 5;
    int hc = ((lane >> 4) & 1) * 128 + (lane & 15) * 8;

    u32x4 qw = *(const u32x4*)&Qb[(size_t)node * 256 + hc];
    float4 wea = *(const float4*)&We[hc];
    float4 web = *(const float4*)&We[hc + 4];
    float q[8];
    #pragma unroll
    for (int t = 0; t < 4; ++t) { q[2 * t] = bflo(qw[t]); q[2 * t + 1] = bfhi(qw[t]); }
    float wv[8] = {wea.x, wea.y, wea.z, wea.w, web.x, web.y, web.z, web.w};

    const float scale = 0.08838834764831845f;   // 1/sqrt(128)
    float qwe = 0.f;
    #pragma unroll
    for (int t = 0; t < 8; ++t) qwe += q[t] * wv[t];
    qwe += __shfl_xor(qwe, 1, 64);
    qwe += __shfl_xor(qwe, 2, 64);
    qwe += __shfl_xor(qwe, 4, 64);
    qwe += __shfl_xor(qwe, 8, 64);
    float qwes = qwe * scale;

    int beg = rowstart[node], end = rowstart[node + 1];
    const unsigned short* KV = KVb + hc;

    float ssum = 0.f, wa = 0.f;
    float acc[8] = {0.f, 0.f, 0.f, 0.f, 0.f, 0.f, 0.f, 0.f};

    auto process = [&](const u32x4& kk, const u32x4& vv, float a, bool valid) {
        float s = 0.f;
        #pragma unroll
        for (int t = 0; t < 4; ++t)
            s += q[2 * t] * bflo(kk[t]) + q[2 * t + 1] * bfhi(kk[t]);
        s += __shfl_xor(s, 1, 64);
        s += __shfl_xor(s, 2, 64);
        s += __shfl_xor(s, 4, 64);
        s += __shfl_xor(s, 8, 64);
        float w = valid ? __expf(s * scale + a * qwes) : 0.f;
        ssum += w;
        wa += w * a;
        #pragma unroll
        for (int t = 0; t < 4; ++t) {
            acc[2 * t]     += w * bflo(vv[t]);
            acc[2 * t + 1] += w * bfhi(vv[t]);
        }
    };

    for (int i0 = beg; i0 < end; i0 += 8) {
        bool val[4];
        float aval[4];
        u32x4 kw[4], vw[4];
        #pragma unroll
        for (int j = 0; j < 4; ++j) {
            int i = i0 + 2 * j + epar;
            val[j] = i < end;
            int2 se = sae[val[j] ? i : beg];
            aval[j] = __int_as_float(se.y);
            const unsigned short* kp = KV + (size_t)se.x * 512;
            kw[j] = *(const u32x4*)kp;
            vw[j] = *(const u32x4*)(kp + 256);
        }
        #pragma unroll
        for (int j = 0; j < 4; ++j)
            process(kw[j], vw[j], aval[j], val[j]);
    }

    // merge the two edge-slot partials (lane ^ 32)
    float sw = ssum + __shfl_xor(ssum, 32, 64);
    float waw = wa + __shfl_xor(wa, 32, 64);
    float o[8];
    #pragma unroll
    for (int t = 0; t < 8; ++t)
        o[t] = acc[t] + __shfl_xor(acc[t], 32, 64);

    if (epar == 0) {
        float inv = 1.0f / (sw + 1e-16f);
        u32x4 skw = *(const u32x4*)&Sb[(size_t)node * 256 + hc];
        float sk[8];
        #pragma unroll
        for (int t = 0; t < 4; ++t) { sk[2 * t] = bflo(skw[t]); sk[2 * t + 1] = bfhi(skw[t]); }
        float r[8];
        #pragma unroll
        for (int t = 0; t < 8; ++t)
            r[t] = (o[t] + waw * wv[t]) * inv + sk[t];
        if (OUTBF) {
            u32x4 ob;
            #pragma unroll
            for (int t = 0; t < 4; ++t)
                ob[t] = (unsigned)f2bf(r[2 * t]) | ((unsigned)f2bf(r[2 * t + 1]) << 16);
            *(u32x4*)&outb[(size_t)node * 256 + hc] = ob;
        } else {
            *(float4*)&outf[(size_t)node * 256 + hc] = make_float4(r[0], r[1], r[2], r[3]);
            *(float4*)&outf[(size_t)node * 256 + hc + 4] = make_float4(r[4], r[5], r[6], r[7]);
        }
    }
}

// ---------------- BatchNorm ----------------
template <int BF>
__global__ void bn_stats(const void* __restrict__ xv, float* __restrict__ sums, int n) {
    int c = threadIdx.x;  // 256
    float s = 0.f, s2 = 0.f;
    if (BF) {
        const unsigned short* x = (const unsigned short*)xv;
        for (int r = blockIdx.x; r < n; r += gridDim.x) {
            float v = __uint_as_float((unsigned)x[(size_t)r * 256 + c] << 16);
            s += v; s2 += v * v;
        }
    } else {
        const float* x = (const float*)xv;
        for (int r = blockIdx.x; r < n; r += gridDim.x) {
            float v = x[(size_t)r * 256 + c];
            s += v; s2 += v * v;
        }
    }
    atomicAdd(&sums[c], s);
    atomicAdd(&sums[256 + c], s2);
}

__global__ void bn_apply(const float* __restrict__ x, const float* __restrict__ sums,
                         const float* __restrict__ g, const float* __restrict__ b,
                         float* __restrict__ y, int n) {
    int idx = blockIdx.x * blockDim.x + threadIdx.x;
    if (idx >= n * 256) return;
    int c = idx & 255;
    float invn = 1.0f / (float)n;
    float mu = sums[c] * invn;
    float var = sums[256 + c] * invn - mu * mu;
    float v = (x[idx] - mu) * rsqrtf(var + BN_EPS) * g[c] + b[c];
    y[idx] = fmaxf(v, 0.f);
}

extern "C" void kernel_launch(void* const* d_in, const int* in_sizes, int n_in,
                              void* d_out, int out_size, void* d_ws, size_t ws_size,
                              hipStream_t stream) {
    const float* x         = (const float*)d_in[0];
    const int*   edge_idx  = (const int*)d_in[1];
    const float* edge_attr = (const float*)d_in[2];
    const float* Wq1 = (const float*)d_in[3];  const float* bq1 = (const float*)d_in[4];
    const float* Wk1 = (const float*)d_in[5];  const float* bk1 = (const float*)d_in[6];
    const float* Wv1 = (const float*)d_in[7];  const float* bv1 = (const float*)d_in[8];
    const float* We1 = (const float*)d_in[9];
    const float* Ws1 = (const float*)d_in[10]; const float* bs1 = (const float*)d_in[11];
    const float* g1  = (const float*)d_in[12]; const float* b1  = (const float*)d_in[13];
    const float* Wq2 = (const float*)d_in[14]; const float* bq2 = (const float*)d_in[15];
    const float* Wk2 = (const float*)d_in[16]; const float* bk2 = (const float*)d_in[17];
    const float* Wv2 = (const float*)d_in[18]; const float* bv2 = (const float*)d_in[19];
    const float* We2 = (const float*)d_in[20];
    const float* Ws2 = (const float*)d_in[21]; const float* bs2 = (const float*)d_in[22];
    const float* g2  = (const float*)d_in[23]; const float* b2  = (const float*)d_in[24];

    const int N = in_sizes[0] / 128;   // 10000
    const int E = in_sizes[1] / 2;     // 160000
    const int* src = edge_idx;
    const int* dst = edge_idx + E;

    char* ws = (char*)d_ws;
    size_t off = 0;
    auto alloc = [&](size_t bytes) -> void* {
        void* p = ws + off;
        off += (bytes + 255) & ~(size_t)255;
        return p;
    };
    unsigned short* Qb       = (unsigned short*)alloc((size_t)N * 256 * 2);
    unsigned short* KVb      = (unsigned short*)alloc((size_t)N * 512 * 2);
    unsigned short* Sb       = (unsigned short*)alloc((size_t)N * 256 * 2);
    float*          attn_out = (float*)alloc((size_t)N * 256 * 4);
    unsigned short* h1b      = (unsigned short*)alloc((size_t)N * 256 * 2);
    unsigned short* xb       = (unsigned short*)alloc((size_t)N * 128 * 2);
    unsigned short* Wt1      = (unsigned short*)alloc((size_t)1024 * 128 * 2);
    unsigned short* Wt2      = (unsigned short*)alloc((size_t)1024 * 256 * 2);
    float*          bcat1    = (float*)alloc(1024 * 4);
    float*          bcat2    = (float*)alloc(1024 * 4);
    int*            deg      = (int*)alloc((size_t)N * 4);
    int*            rowstart = (int*)alloc((size_t)(N + 1) * 4);
    int*            cursor   = (int*)alloc((size_t)N * 4);
    int2*           sae      = (int2*)alloc((size_t)E * 8);
    float*          bns1     = (float*)alloc(512 * 4);
    float*          bns2     = (float*)alloc(512 * 4);

    const int n4 = N * 128 / 4;
    const float invn = 1.0f / (float)N;

    prep_kernel<<<96 + (n4 + 255) / 256, 256, 0, stream>>>(
        x, Wq1, Wk1, Wv1, Ws1, bq1, bk1, bv1, bs1,
        Wq2, Wk2, Wv2, Ws2, bq2, bk2, bv2, bs2,
        xb, Wt1, Wt2, bcat1, bcat2, deg, cursor, bns1, bns2, N, n4);
    hist_kernel<<<(E + 255) / 256, 256, 0, stream>>>(dst, deg, E);
    scan_excl<<<1, 1024, 0, stream>>>(deg, rowstart, N);
    scatter_kernel<<<(E + 255) / 256, 256, 0, stream>>>(src, dst, edge_attr, rowstart, cursor,
                                                        sae, E);

    const int gx = (N + 127) / 128;                 // 79 row-strips
    const int gemm_blocks = ((gx + 7) / 8) * 64;    // swizzled 1D grid (some blocks idle)
    int attn_blocks = (N + 3) / 4;

    // ---- layer 1 (K = 128) ----
    gemm_core<0><<<gemm_blocks, 256, 0, stream>>>(xb, Wt1, bcat1, nullptr, nullptr, nullptr, 0.f,
                                                  Qb, KVb, Sb, N, 128, gx);
    attn_kernel<1><<<attn_blocks, 256, 0, stream>>>(Qb, KVb, Sb, sae, We1, rowstart,
                                                    nullptr, h1b, N);
    bn_stats<1><<<256, 256, 0, stream>>>(h1b, bns1, N);

    // ---- layer 2 (K = 256), BN1+ReLU fused into A-staging (bf16 h1) ----
    gemm_core<1><<<gemm_blocks, 256, 0, stream>>>(h1b, Wt2, bcat2, bns1, g1, b1, invn,
                                                  Qb, KVb, Sb, N, 256, gx);
    attn_kernel<0><<<attn_blocks, 256, 0, stream>>>(Qb, KVb, Sb, sae, We2, rowstart,
                                                    attn_out, nullptr, N);
    bn_stats<0><<<256, 256, 0, stream>>>(attn_out, bns2, N);
    bn_apply<<<(N * 256 + 255) / 256, 256, 0, stream>>>(attn_out, bns2, g2, b2, (float*)d_out, N);
}